// Round 5
// baseline (262.997 us; speedup 1.0000x reference)
//
#include <hip/hip_runtime.h>
#include <stdint.h>

// ---------------------------------------------------------------------------
// CrossAttention (b=16, c=1024, dim=1024), fp32 in/out, bf16 MFMA internally.
//   1. cvt fp32->bf16: x->XB, cond->CB, Wq->WQB, Wkv->WKVB
//   2. Q  = XB @ WQB^T                      (bf16 out)
//   3. KV = CB @ WKVB^T  -> K (bf16), V^T   (bf16, transposed in epilogue)
//   4. S  = Q @ K^T * 1/32  per batch       (fp32, overlays XB/CB)
//   5. P  = softmax_rows(S)                 (bf16, overlays Q)
//   6. out= P @ (V^T)^T  per batch          (fp32 -> d_out)
// GEMM R5: 256x256 tile, BK=32, 4-slot LDS ring per operand (deep prefetch:
// stage tile t+3 during tile t; counted vmcnt(8) leaves 2 tiles in flight).
// 2 phases/K-tile {ds_reads | stage | BAR | 16 MFMA | [vm] | BAR}; 64B-row
// swizzle chunk^=((row>>1)&3) (2-way max = free); T1 XCD swizzle; T5 setprio.
// ---------------------------------------------------------------------------

typedef __bf16 bf16_t;
typedef bf16_t bf16x8 __attribute__((ext_vector_type(8)));
typedef float f32x4 __attribute__((ext_vector_type(4)));

#define AS1 __attribute__((address_space(1)))
#define AS3 __attribute__((address_space(3)))

__device__ __forceinline__ uint16_t f2bf(float f) {
  bf16_t h = (bf16_t)f;  // RNE
  return __builtin_bit_cast(uint16_t, h);
}

// ---- fp32 -> bf16 conversion, float4-vectorized ----
__global__ __launch_bounds__(256) void cvt_bf16(const float* __restrict__ in,
                                                uint16_t* __restrict__ out, int n4) {
  int i = blockIdx.x * 256 + threadIdx.x;
  if (i >= n4) return;
  float4 v = ((const float4*)in)[i];
  ushort4 o;
  o.x = f2bf(v.x); o.y = f2bf(v.y); o.z = f2bf(v.z); o.w = f2bf(v.w);
  ((ushort4*)out)[i] = o;
}

// ---- stage one 256x32 bf16 K-tile (16 KiB) global -> LDS ----
// LDS dest linear (global_load_lds requirement); global SOURCE chunk-XOR
// pre-swizzled (rule #21): 64B rows, 4 chunks/row, sch = ch ^ ((row>>1)&3).
// Readers use chunk ^= ((row>>1)&3): bank map = 16*(row&1) + 4*chunk -> 8
// distinct 16B slots per 16 lanes = 2-way max (free, m136).
__device__ __forceinline__ void stage32(const uint16_t* __restrict__ g, int ldK,
                                        uint16_t* lds, int tid) {
#pragma unroll
  for (int i = 0; i < 2; ++i) {
    int c = i * 512 + tid;              // 16B-chunk index, 0..1023
    int row = c >> 2;                   // 0..255
    int ch = c & 3;                     // chunk within 64B row
    int sch = ch ^ ((row >> 1) & 3);    // involutive source swizzle
    const uint16_t* gp = g + row * ldK + sch * 8;
    __builtin_amdgcn_global_load_lds((AS1 void*)gp,
                                     (AS3 void*)((uint8_t*)lds + c * 16), 16, 0,
                                     0);
  }
}

// ---- 256x256-tile A·B^T GEMM, bf16 in, fp32 accum, ring-4 pipelined ----
// MODE 0: C0 = bf16, ldc = N
// MODE 1: kv-split: col<1024 -> K (bf16 row-major); col>=1024 -> V^T
// MODE 2: C0 = fp32 * scale, batched via blockIdx.z (strides in elements)
template <int MODE>
__global__ __launch_bounds__(512, 2) void gemm_bt(
    const uint16_t* __restrict__ A, const uint16_t* __restrict__ B,
    void* __restrict__ C0, void* __restrict__ C1, int K, int N,
    long long sA, long long sB, long long sC, float scale) {
  __shared__ uint16_t As[4][8192];  // [slot][256 rows x 32 cols] 16 KiB each
  __shared__ uint16_t Bs[4][8192];

  const int tid = threadIdx.x;
  const int lane = tid & 63;
  const int wid = tid >> 6;   // 0..7
  const int wr = wid >> 2;    // 0..1 : M wave row (128 rows each)
  const int wc = wid & 3;     // 0..3 : N wave col (64 cols each)
  const int lr = lane & 15, lg = lane >> 4;
  // reader swizzle: chunk = lg ^ ((row>>1)&3); row%16 == lr for all frags
  const int chnk = ((lg ^ ((lr >> 1) & 3)) << 4);

  // T1: bijective XCD-chunked blockIdx swizzle (nwg % 8 == 0 for all grids)
  const int gx = gridDim.x, gy = gridDim.y;
  const int nwg = gx * gy * gridDim.z;
  int fid = blockIdx.x + gx * (blockIdx.y + gy * blockIdx.z);
  int swz = (fid & 7) * (nwg >> 3) + (fid >> 3);
  const int bx = swz % gx;
  const int rem = swz / gx;
  const int by = rem % gy;
  const int bz = rem / gy;

  const int row0 = by * 256;
  const int col0 = bx * 256;
  const uint16_t* At = A + (long long)bz * sA + (long long)row0 * K;
  const uint16_t* Bt = B + (long long)bz * sB + (long long)col0 * K;

  const int NT = K >> 5;  // 32-wide K-tiles (32 here); requires NT >= 3

  // ---- prologue: stage tiles 0,1,2 (A+B) = 12 loads/thread ----
  stage32(At, K, &As[0][0], tid);
  stage32(Bt, K, &Bs[0][0], tid);
  stage32(At + 32, K, &As[1][0], tid);
  stage32(Bt + 32, K, &Bs[1][0], tid);
  stage32(At + 64, K, &As[2][0], tid);
  stage32(Bt + 64, K, &Bs[2][0], tid);
  asm volatile("s_waitcnt vmcnt(8)" ::: "memory");  // tile 0 landed
  __builtin_amdgcn_s_barrier();

  f32x4 acc[8][4] = {};

  for (int t = 0; t < NT; ++t) {
    const uint16_t* sa = &As[t & 3][0];
    const uint16_t* sb = &Bs[t & 3][0];
    const int tp = t + 3;  // prefetch target

    // ---- ph0: A frags (8) + B frags nj=0,1 (2); stage A(t+3); 16 MFMA ----
    bf16x8 fa[8], fb0, fb1;
#pragma unroll
    for (int mi = 0; mi < 8; ++mi)
      fa[mi] = *(const bf16x8*)((const uint8_t*)sa +
                                (wr * 128 + mi * 16 + lr) * 64 + chnk);
    fb0 = *(const bf16x8*)((const uint8_t*)sb + (wc * 64 + 0 * 16 + lr) * 64 +
                           chnk);
    fb1 = *(const bf16x8*)((const uint8_t*)sb + (wc * 64 + 1 * 16 + lr) * 64 +
                           chnk);
    if (tp < NT) stage32(At + tp * 32, K, &As[tp & 3][0], tid);
    __builtin_amdgcn_s_barrier();
    __builtin_amdgcn_s_setprio(1);
#pragma unroll
    for (int mi = 0; mi < 8; ++mi) {
      acc[mi][0] = __builtin_amdgcn_mfma_f32_16x16x32_bf16(fa[mi], fb0,
                                                           acc[mi][0], 0, 0, 0);
      acc[mi][1] = __builtin_amdgcn_mfma_f32_16x16x32_bf16(fa[mi], fb1,
                                                           acc[mi][1], 0, 0, 0);
    }
    __builtin_amdgcn_s_setprio(0);
    __builtin_amdgcn_s_barrier();

    // ---- ph1: B frags nj=2,3 (2); stage B(t+3); 16 MFMA; counted wait ----
    bf16x8 fb2, fb3;
    fb2 = *(const bf16x8*)((const uint8_t*)sb + (wc * 64 + 2 * 16 + lr) * 64 +
                           chnk);
    fb3 = *(const bf16x8*)((const uint8_t*)sb + (wc * 64 + 3 * 16 + lr) * 64 +
                           chnk);
    if (tp < NT) stage32(Bt + tp * 32, K, &Bs[tp & 3][0], tid);
    __builtin_amdgcn_s_barrier();
    __builtin_amdgcn_s_setprio(1);
#pragma unroll
    for (int mi = 0; mi < 8; ++mi) {
      acc[mi][2] = __builtin_amdgcn_mfma_f32_16x16x32_bf16(fa[mi], fb2,
                                                           acc[mi][2], 0, 0, 0);
      acc[mi][3] = __builtin_amdgcn_mfma_f32_16x16x32_bf16(fa[mi], fb3,
                                                           acc[mi][3], 0, 0, 0);
    }
    __builtin_amdgcn_s_setprio(0);
    // derived wait: complete tile t+1's 4 loads; leave later tiles in flight
    if (t + 3 < NT)
      asm volatile("s_waitcnt vmcnt(8)" ::: "memory");
    else if (t + 2 < NT)
      asm volatile("s_waitcnt vmcnt(4)" ::: "memory");
    else if (t + 1 < NT)
      asm volatile("s_waitcnt vmcnt(0)" ::: "memory");
    __builtin_amdgcn_s_barrier();
  }

  // ---- epilogue: C/D layout col=lane&15, row=(lane>>4)*4+j ----
#pragma unroll
  for (int mi = 0; mi < 8; ++mi) {
#pragma unroll
    for (int ni = 0; ni < 4; ++ni) {
      const int row = row0 + wr * 128 + mi * 16 + lg * 4;  // +j
      const int col = col0 + wc * 64 + ni * 16 + lr;
      if (MODE == 0) {
        uint16_t* C = (uint16_t*)C0;
#pragma unroll
        for (int j = 0; j < 4; ++j)
          C[(long long)(row + j) * N + col] = f2bf(acc[mi][ni][j]);
      } else if (MODE == 1) {
        if (col < 1024) {
          uint16_t* Kp = (uint16_t*)C0;
#pragma unroll
          for (int j = 0; j < 4; ++j)
            Kp[(long long)(row + j) * 1024 + col] = f2bf(acc[mi][ni][j]);
        } else {
          const int b = row >> 10, jj = row & 1023;
          ushort4 o;
          o.x = f2bf(acc[mi][ni][0]);
          o.y = f2bf(acc[mi][ni][1]);
          o.z = f2bf(acc[mi][ni][2]);
          o.w = f2bf(acc[mi][ni][3]);
          uint16_t* Vp = (uint16_t*)C1;
          *(ushort4*)(Vp + (long long)b * 1048576 +
                      (long long)(col - 1024) * 1024 + jj) = o;
        }
      } else {
        float* C = (float*)C0;
#pragma unroll
        for (int j = 0; j < 4; ++j)
          C[(long long)bz * sC + (long long)(row + j) * N + col] =
              acc[mi][ni][j] * scale;
      }
    }
  }
}

// ---- row softmax: 16384 rows x 1024 fp32 -> bf16 ----
__global__ __launch_bounds__(256) void softmax_rows(const float* __restrict__ S,
                                                    uint16_t* __restrict__ P) {
  const int row = blockIdx.x;
  const int t = threadIdx.x;
  const int w = t >> 6, l = t & 63;
  __shared__ float red[8];

  const float4 v = ((const float4*)(S + (long long)row * 1024))[t];
  float m = fmaxf(fmaxf(v.x, v.y), fmaxf(v.z, v.w));
#pragma unroll
  for (int o = 1; o < 64; o <<= 1) m = fmaxf(m, __shfl_xor(m, o, 64));
  if (l == 0) red[w] = m;
  __syncthreads();
  m = fmaxf(fmaxf(red[0], red[1]), fmaxf(red[2], red[3]));

  float e0 = __expf(v.x - m), e1 = __expf(v.y - m);
  float e2 = __expf(v.z - m), e3 = __expf(v.w - m);
  float s = e0 + e1 + e2 + e3;
#pragma unroll
  for (int o = 1; o < 64; o <<= 1) s += __shfl_xor(s, o, 64);
  if (l == 0) red[4 + w] = s;
  __syncthreads();
  s = red[4] + red[5] + red[6] + red[7];
  const float inv = 1.0f / s;

  ushort4 o4;
  o4.x = f2bf(e0 * inv); o4.y = f2bf(e1 * inv);
  o4.z = f2bf(e2 * inv); o4.w = f2bf(e3 * inv);
  ((ushort4*)P)[(long long)row * 256 + t] = o4;
}

extern "C" void kernel_launch(void* const* d_in, const int* in_sizes, int n_in,
                              void* d_out, int out_size, void* d_ws, size_t ws_size,
                              hipStream_t stream) {
  const float* x    = (const float*)d_in[0];
  const float* cond = (const float*)d_in[1];
  const float* Wq   = (const float*)d_in[2];
  const float* Wkv  = (const float*)d_in[3];
  float* out = (float*)d_out;

  uint8_t* ws = (uint8_t*)d_ws;
  const long long MiB = 1ll << 20;
  // layout (166 MiB peak): S(fp32,64Mi) overlays XB+CB; P overlays Q.
  uint16_t* XB   = (uint16_t*)(ws + 0 * MiB);    // 32 MiB
  uint16_t* CB   = (uint16_t*)(ws + 32 * MiB);   // 32 MiB
  float*    S    = (float*)(ws + 0 * MiB);       // 64 MiB (after projections)
  uint16_t* WQB  = (uint16_t*)(ws + 64 * MiB);   // 2 MiB
  uint16_t* WKVB = (uint16_t*)(ws + 66 * MiB);   // 4 MiB
  uint16_t* Q    = (uint16_t*)(ws + 70 * MiB);   // 32 MiB (later P)
  uint16_t* Kb   = (uint16_t*)(ws + 102 * MiB);  // 32 MiB
  uint16_t* VT   = (uint16_t*)(ws + 134 * MiB);  // 32 MiB

  // 1. conversions
  cvt_bf16<<<16384, 256, 0, stream>>>(x, XB, 16777216 / 4);
  cvt_bf16<<<16384, 256, 0, stream>>>(cond, CB, 16777216 / 4);
  cvt_bf16<<<1024, 256, 0, stream>>>(Wq, WQB, 1048576 / 4);
  cvt_bf16<<<2048, 256, 0, stream>>>(Wkv, WKVB, 2097152 / 4);

  // 2. Q = XB @ WQB^T   (M=16384, N=1024, K=1024) -> 256 blocks (1/CU)
  gemm_bt<0><<<dim3(4, 64, 1), 512, 0, stream>>>(XB, WQB, Q, nullptr, 1024,
                                                 1024, 0, 0, 0, 1.0f);
  // 3. KV = CB @ WKVB^T (M=16384, N=2048) -> K, V^T  (512 blocks)
  gemm_bt<1><<<dim3(8, 64, 1), 512, 0, stream>>>(CB, WKVB, Kb, VT, 1024, 2048,
                                                 0, 0, 0, 1.0f);
  // 4. S = Q @ K^T * 1/32, batched over 16 (256 blocks)
  gemm_bt<2><<<dim3(4, 4, 16), 512, 0, stream>>>(Q, Kb, S, nullptr, 1024, 1024,
                                                 1048576, 1048576, 1048576,
                                                 0.03125f);
  // 5. P = softmax(S) -> bf16, overlays Q
  softmax_rows<<<16384, 256, 0, stream>>>(S, Q);
  // 6. out = P @ (V^T)^T, batched over 16 (256 blocks)
  gemm_bt<2><<<dim3(4, 4, 16), 512, 0, stream>>>(Q, VT, out, nullptr, 1024,
                                                 1024, 1048576, 1048576,
                                                 1048576, 1.0f);
}

// Round 7
// 239.655 us; speedup vs baseline: 1.0974x; 1.0974x over previous
//
#include <hip/hip_runtime.h>
#include <stdint.h>

// ---------------------------------------------------------------------------
// CrossAttention (b=16, c=1024, dim=1024), fp32 in/out, bf16 MFMA internally.
//   1. cvt fp32->bf16 (one fused kernel): x->XB, cond->CB, Wq->WQB, Wkv->WKVB
//   2. Q  = XB @ WQB^T                      (bf16 out)
//   3. KV = CB @ WKVB^T  -> K (bf16), V^T   (bf16, LDS-transposed epilogue)
//   4. S  = Q @ K^T * 1/32  per batch       (fp32, overlays XB/CB)
//   5. P  = softmax_rows(S)                 (bf16, overlays Q)
//   6. out= P @ (V^T)^T  per batch          (fp32 -> d_out)
// GEMM: 256x256 tile, BK=64, 8 waves (2Mx4N), 2 phases/K-tile with
// cross-phase pipelined ds_reads (aB_ prefetch overlaps ph0's MFMA via the
// compiler's counted FIFO lgkm wait). R7 fixes vs R6:
//  (a) cvt_all grid 34816->35840 (V-half of Wkv was never converted!)
//  (b) lgkmcnt(0) after ph(t,0)'s MFMA, before its barrier: drains the aB_
//      reads of buf[t&1] before ph(t,1) stages into that same buffer (WAR).
// ---------------------------------------------------------------------------

typedef __bf16 bf16_t;
typedef bf16_t bf16x8 __attribute__((ext_vector_type(8)));
typedef float f32x4 __attribute__((ext_vector_type(4)));

#define AS1 __attribute__((address_space(1)))
#define AS3 __attribute__((address_space(3)))

__device__ __forceinline__ uint16_t f2bf(float f) {
  bf16_t h = (bf16_t)f;  // RNE
  return __builtin_bit_cast(uint16_t, h);
}

// ---- fused fp32 -> bf16 conversion for all 4 tensors, float4-vectorized ----
// total float4 = (16777216 + 16777216 + 1048576 + 2097152)/4 = 9,175,040
__global__ __launch_bounds__(256) void cvt_all(
    const float* __restrict__ x, const float* __restrict__ c,
    const float* __restrict__ wq, const float* __restrict__ wkv,
    uint16_t* __restrict__ XB, uint16_t* __restrict__ CB,
    uint16_t* __restrict__ WQB, uint16_t* __restrict__ WKVB) {
  long i = (long)blockIdx.x * 256 + threadIdx.x;  // float4 index
  if (i >= 9175040) return;
  const float* src;
  uint16_t* dst;
  long off;
  if (i < 4194304) { src = x; dst = XB; off = i; }
  else if (i < 8388608) { src = c; dst = CB; off = i - 4194304; }
  else if (i < 8650752) { src = wq; dst = WQB; off = i - 8388608; }
  else { src = wkv; dst = WKVB; off = i - 8650752; }
  float4 v = ((const float4*)src)[off];
  ushort4 o;
  o.x = f2bf(v.x); o.y = f2bf(v.y); o.z = f2bf(v.z); o.w = f2bf(v.w);
  ((ushort4*)dst)[off] = o;
}

// ---- stage one 256x64 bf16 K-tile (32 KiB) global -> LDS (4 loads/thread) --
// LDS dest linear (global_load_lds requirement); global SOURCE chunk-XOR
// pre-swizzled (rule #21) so readers use chunk^=(row&7), conflict-free.
__device__ __forceinline__ void stage_tile(const uint16_t* __restrict__ g,
                                           int ldK, uint16_t* lds, int tid) {
#pragma unroll
  for (int i = 0; i < 4; ++i) {
    int cix = i * 512 + tid;            // 16B-chunk index, 0..2047
    int row = cix >> 3;                 // 0..255
    int ch = cix & 7;                   // chunk within 128B row
    int sch = ch ^ (row & 7);           // involutive source swizzle
    const uint16_t* gp = g + row * ldK + sch * 8;
    __builtin_amdgcn_global_load_lds((AS1 void*)gp,
                                     (AS3 void*)((uint8_t*)lds + cix * 16), 16,
                                     0, 0);
  }
}

// ---- 256x256-tile A·B^T GEMM, bf16 in, fp32 accum, lgkm-pipelined ----
// MODE 0: C0 = bf16, ldc = N
// MODE 1: kv-split: col<1024 -> K (bf16 row-major); col>=1024 -> V^T via
//         LDS transpose (coalesced global writes)
// MODE 2: C0 = fp32 * scale, batched via blockIdx.z (strides in elements)
template <int MODE>
__global__ __launch_bounds__(512, 2) void gemm_bt(
    const uint16_t* __restrict__ A, const uint16_t* __restrict__ B,
    void* __restrict__ C0, void* __restrict__ C1, int K, int N,
    long long sA, long long sB, long long sC, float scale) {
  // 128 KiB flat: A-buf0 [0,16384) A-buf1 [16384,32768) B-buf0 [32768,49152)
  // B-buf1 [49152,65536)  (u16 units; each buf = 256 rows x 64 cols)
  __shared__ uint16_t smem[65536];

  const int tid = threadIdx.x;
  const int lane = tid & 63;
  const int wid = tid >> 6;   // 0..7
  const int wr = wid >> 2;    // 0..1 : M wave row (128 rows each)
  const int wc = wid & 3;     // 0..3 : N wave col (64 cols each)
  const int lr = lane & 15, lg = lane >> 4;
  const int ch0 = lr & 7;     // reader swizzle parity (== row&7 for all frags)

  // T1: bijective XCD-chunked blockIdx swizzle (nwg % 8 == 0 for all grids).
  const int gx = gridDim.x, gy = gridDim.y;
  const int nwg = gx * gy * gridDim.z;
  int fid = blockIdx.x + gx * (blockIdx.y + gy * blockIdx.z);
  int swz = (fid & 7) * (nwg >> 3) + (fid >> 3);
  const int bx = swz % gx;
  const int rem = swz / gx;
  const int by = rem % gy;
  const int bz = rem / gy;

  const int row0 = by * 256;
  const int col0 = bx * 256;
  const uint16_t* At = A + (long long)bz * sA + (long long)row0 * K;
  const uint16_t* Bt = B + (long long)bz * sB + (long long)col0 * K;

  const int NT = K >> 6;  // 64-wide K-tiles (16 here); requires NT >= 2

  // ---- prologue: stage tiles 0,1 (A+B) = 16 loads; wait tile 0 ----
  stage_tile(At, K, smem, tid);
  stage_tile(Bt, K, smem + 32768, tid);
  stage_tile(At + 64, K, smem + 16384, tid);
  stage_tile(Bt + 64, K, smem + 49152, tid);
  asm volatile("s_waitcnt vmcnt(8)" ::: "memory");  // tile0 landed; t1 flies
  __builtin_amdgcn_s_barrier();

  f32x4 acc[8][4] = {};
  bf16x8 aA_[4][2];  // A(t, H0) fragments (prefetched previous phase)
  bf16x8 aB_[4][2];  // A(t, H1) fragments (prefetched in ph(t,0))
  bf16x8 bF[4][2];   // B(t) fragments, whole tile (read in-phase at ph(t,0))

  // preload aA_ = A(0, H0)
  {
    const uint8_t* sa = (const uint8_t*)smem;
#pragma unroll
    for (int mi = 0; mi < 4; ++mi)
#pragma unroll
      for (int kk = 0; kk < 2; ++kk)
        aA_[mi][kk] = *(const bf16x8*)(sa + (wr * 128 + mi * 16 + lr) * 128 +
                                       (((kk * 4 + lg) ^ ch0) << 4));
  }

  for (int t = 0; t < NT; ++t) {
    const uint8_t* sa = (const uint8_t*)(smem + (t & 1) * 16384);
    const uint8_t* sb = (const uint8_t*)(smem + 32768 + (t & 1) * 16384);

    // ============ phase (t,0): MFMA on {aA_, bF}; prefetch aB_ ============
    // b(t) reads FIRST (oldest in lgkm FIFO), then aB_ prefetch: the MFMA's
    // compiler wait (counted lgkm) completes bF while leaving aB_ outstanding
    // under the MFMA cluster.
#pragma unroll
    for (int nj = 0; nj < 4; ++nj)
#pragma unroll
      for (int kk = 0; kk < 2; ++kk)
        bF[nj][kk] =
            *(const bf16x8*)(sb + (wc * 64 + nj * 16 + lr) * 128 +
                             (((kk * 4 + lg) ^ ch0) << 4));
#pragma unroll
    for (int mi = 0; mi < 4; ++mi)
#pragma unroll
      for (int kk = 0; kk < 2; ++kk)
        aB_[mi][kk] =
            *(const bf16x8*)(sa + (wr * 128 + 64 + mi * 16 + lr) * 128 +
                             (((kk * 4 + lg) ^ ch0) << 4));
    __builtin_amdgcn_s_setprio(1);
#pragma unroll
    for (int kk = 0; kk < 2; ++kk)
#pragma unroll
      for (int mi = 0; mi < 4; ++mi)
#pragma unroll
        for (int nj = 0; nj < 4; ++nj)
          acc[mi][nj] = __builtin_amdgcn_mfma_f32_16x16x32_bf16(
              aA_[mi][kk], bF[nj][kk], acc[mi][nj], 0, 0, 0);
    __builtin_amdgcn_s_setprio(0);
    // derived: completes A(t+1) [needed by ph(t,1)'s aA_ refill]
    if (t + 1 < NT) asm volatile("s_waitcnt vmcnt(4)" ::: "memory");
    // WAR fence (R7 fix): drain this wave's aB_ reads of buf[t&1] before the
    // barrier, so ph(t,1)'s stages into buf[t&1] can't clobber pending reads.
    asm volatile("s_waitcnt lgkmcnt(0)" ::: "memory");
    __builtin_amdgcn_s_barrier();

    // ============ phase (t,1): stages; MFMA on {aB_, bF}; refill aA_ ========
    // stage targets (buf t&1) are read-complete block-wide by the barrier.
    if (t + 2 < NT) {
      stage_tile(At + (t + 2) * 64, K, smem + (t & 1) * 16384, tid);
      stage_tile(Bt + (t + 2) * 64, K, smem + 32768 + (t & 1) * 16384, tid);
    }
    if (t + 1 < NT) {
      const uint8_t* sa2 = (const uint8_t*)(smem + ((t + 1) & 1) * 16384);
#pragma unroll
      for (int mi = 0; mi < 4; ++mi)
#pragma unroll
        for (int kk = 0; kk < 2; ++kk)
          aA_[mi][kk] =
              *(const bf16x8*)(sa2 + (wr * 128 + mi * 16 + lr) * 128 +
                               (((kk * 4 + lg) ^ ch0) << 4));
    }
    __builtin_amdgcn_s_setprio(1);
#pragma unroll
    for (int kk = 0; kk < 2; ++kk)
#pragma unroll
      for (int mi = 0; mi < 4; ++mi)
#pragma unroll
        for (int nj = 0; nj < 4; ++nj)
          acc[4 + mi][nj] = __builtin_amdgcn_mfma_f32_16x16x32_bf16(
              aB_[mi][kk], bF[nj][kk], acc[4 + mi][nj], 0, 0, 0);
    __builtin_amdgcn_s_setprio(0);
    // derived: completes B(t+1) [needed by ph(t+1,0)]; leaves t+2's 8 flying.
    // aA_ refill reads (buf (t+1)&1) may stay lgkm-outstanding across this
    // barrier: ph(t+1,0) only READS that buffer; the next write to it is in
    // ph(t+1,1), which is after ph(t+1,0)'s MFMA consumed aA_ (compiler wait)
    // and after ph(t+1,0)'s block-wide barrier. WAR-safe.
    if (t + 2 < NT)
      asm volatile("s_waitcnt vmcnt(8)" ::: "memory");
    else
      asm volatile("s_waitcnt vmcnt(0)" ::: "memory");
    __builtin_amdgcn_s_barrier();
  }

  // ---- epilogue: C/D layout col=lane&15, row=(lane>>4)*4+j ----
  if (MODE == 1 && col0 >= 1024) {
    // V^T via LDS transpose: acc -> smem[cc][jj^swz] -> coalesced 16B stores
    __syncthreads();  // main loop fully done (drains all counters); smem free
#pragma unroll
    for (int mi = 0; mi < 8; ++mi) {
#pragma unroll
      for (int ni = 0; ni < 4; ++ni) {
        const int cc = wc * 64 + ni * 16 + lr;         // local col 0..255
        const int jjb = wr * 128 + mi * 16 + lg * 4;   // local row 0..255
        ushort4 o;
        o.x = f2bf(acc[mi][ni][0]);
        o.y = f2bf(acc[mi][ni][1]);
        o.z = f2bf(acc[mi][ni][2]);
        o.w = f2bf(acc[mi][ni][3]);
        *(ushort4*)&smem[cc * 256 + (jjb ^ ((cc & 7) << 3))] = o;
      }
    }
    __syncthreads();
    const int b = row0 >> 10, jj0 = row0 & 1023;
    uint16_t* Vp = (uint16_t*)C1;
#pragma unroll
    for (int k = 0; k < 16; ++k) {
      const int cc = k * 16 + (tid >> 5);
      const int jb = (tid & 31) * 8;
      bf16x8 v = *(const bf16x8*)&smem[cc * 256 + (jb ^ ((cc & 7) << 3))];
      *(bf16x8*)(Vp + (long long)b * 1048576 +
                 (long long)(col0 - 1024 + cc) * 1024 + jj0 + jb) = v;
    }
    return;
  }
#pragma unroll
  for (int mi = 0; mi < 8; ++mi) {
#pragma unroll
    for (int ni = 0; ni < 4; ++ni) {
      const int row = row0 + wr * 128 + mi * 16 + lg * 4;  // +j
      const int col = col0 + wc * 64 + ni * 16 + lr;
      if (MODE == 0 || MODE == 1) {
        uint16_t* C = (uint16_t*)C0;  // MODE1 here: pure-K block (col<1024)
#pragma unroll
        for (int j = 0; j < 4; ++j)
          C[(long long)(row + j) * (MODE == 1 ? 1024 : N) + col] =
              f2bf(acc[mi][ni][j]);
      } else {
        float* C = (float*)C0;
#pragma unroll
        for (int j = 0; j < 4; ++j)
          C[(long long)bz * sC + (long long)(row + j) * N + col] =
              acc[mi][ni][j] * scale;
      }
    }
  }
}

// ---- row softmax: 16384 rows x 1024 fp32 -> bf16 ----
__global__ __launch_bounds__(256) void softmax_rows(const float* __restrict__ S,
                                                    uint16_t* __restrict__ P) {
  const int row = blockIdx.x;
  const int t = threadIdx.x;
  const int w = t >> 6, l = t & 63;
  __shared__ float red[8];

  const float4 v = ((const float4*)(S + (long long)row * 1024))[t];
  float m = fmaxf(fmaxf(v.x, v.y), fmaxf(v.z, v.w));
#pragma unroll
  for (int o = 1; o < 64; o <<= 1) m = fmaxf(m, __shfl_xor(m, o, 64));
  if (l == 0) red[w] = m;
  __syncthreads();
  m = fmaxf(fmaxf(red[0], red[1]), fmaxf(red[2], red[3]));

  float e0 = __expf(v.x - m), e1 = __expf(v.y - m);
  float e2 = __expf(v.z - m), e3 = __expf(v.w - m);
  float s = e0 + e1 + e2 + e3;
#pragma unroll
  for (int o = 1; o < 64; o <<= 1) s += __shfl_xor(s, o, 64);
  if (l == 0) red[4 + w] = s;
  __syncthreads();
  s = red[4] + red[5] + red[6] + red[7];
  const float inv = 1.0f / s;

  ushort4 o4;
  o4.x = f2bf(e0 * inv); o4.y = f2bf(e1 * inv);
  o4.z = f2bf(e2 * inv); o4.w = f2bf(e3 * inv);
  ((ushort4*)P)[(long long)row * 256 + t] = o4;
}

extern "C" void kernel_launch(void* const* d_in, const int* in_sizes, int n_in,
                              void* d_out, int out_size, void* d_ws, size_t ws_size,
                              hipStream_t stream) {
  const float* x    = (const float*)d_in[0];
  const float* cond = (const float*)d_in[1];
  const float* Wq   = (const float*)d_in[2];
  const float* Wkv  = (const float*)d_in[3];
  float* out = (float*)d_out;

  uint8_t* ws = (uint8_t*)d_ws;
  const long long MiB = 1ll << 20;
  // layout (166 MiB peak): S(fp32,64Mi) overlays XB+CB; P overlays Q.
  uint16_t* XB   = (uint16_t*)(ws + 0 * MiB);    // 32 MiB
  uint16_t* CB   = (uint16_t*)(ws + 32 * MiB);   // 32 MiB
  float*    S    = (float*)(ws + 0 * MiB);       // 64 MiB (after projections)
  uint16_t* WQB  = (uint16_t*)(ws + 64 * MiB);   // 2 MiB
  uint16_t* WKVB = (uint16_t*)(ws + 66 * MiB);   // 4 MiB
  uint16_t* Q    = (uint16_t*)(ws + 70 * MiB);   // 32 MiB (later P)
  uint16_t* Kb   = (uint16_t*)(ws + 102 * MiB);  // 32 MiB
  uint16_t* VT   = (uint16_t*)(ws + 134 * MiB);  // 32 MiB

  // 1. fused conversions: 9,175,040 float4 / 256 = 35840 blocks (R7 fix)
  cvt_all<<<35840, 256, 0, stream>>>(x, cond, Wq, Wkv, XB, CB, WQB, WKVB);

  // 2. Q = XB @ WQB^T   (M=16384, N=1024, K=1024) -> 256 blocks (1/CU)
  gemm_bt<0><<<dim3(4, 64, 1), 512, 0, stream>>>(XB, WQB, Q, nullptr, 1024,
                                                 1024, 0, 0, 0, 1.0f);
  // 3. KV = CB @ WKVB^T (M=16384, N=2048) -> K, V^T  (512 blocks)
  gemm_bt<1><<<dim3(8, 64, 1), 512, 0, stream>>>(CB, WKVB, Kb, VT, 1024, 2048,
                                                 0, 0, 0, 1.0f);
  // 4. S = Q @ K^T * 1/32, batched over 16 (256 blocks)
  gemm_bt<2><<<dim3(4, 4, 16), 512, 0, stream>>>(Q, Kb, S, nullptr, 1024, 1024,
                                                 1048576, 1048576, 1048576,
                                                 0.03125f);
  // 5. P = softmax(S) -> bf16, overlays Q
  softmax_rows<<<16384, 256, 0, stream>>>(S, Q);
  // 6. out = P @ (V^T)^T, batched over 16 (256 blocks)
  gemm_bt<2><<<dim3(4, 4, 16), 512, 0, stream>>>(Q, VT, out, nullptr, 1024,
                                                 1024, 1048576, 1048576,
                                                 1048576, 1.0f);
}